// Round 7
// baseline (185.044 us; speedup 1.0000x reference)
//
#include <hip/hip_runtime.h>

//   x        : (B, C, 7, 7) fp32      -> in[0], B*C*49
//   s        : (B, 1, 56, 56) fp32    -> in[1], B*3136
//   feat_mask: (8, 7, 7) fp32         -> in[2], 392
//   sal_idx  : (8, N) int32           -> in[3], 8*N  (N = 406)
// out = [feat (B*C*8) | sal_feat (B*N*8)] fp32
//
// R7: TLP experiment. 32 rows per WAVE (6.27 KB LDS slice), 4 independent
// waves per 256-thread block (NO __syncthreads -- per-wave slices, intra-wave
// ordering via compiler waitcnts). 25 KB/block -> 6 blocks/CU = 24 waves/CU,
// 2x R5's residency. R2/R4/R5/R6 all sat at ~60us with 8-12 waves/CU.

#define KPIX 49
#define WROWS 32                      // rows per wave
#define WFLOATS (WROWS * KPIX)        // 1568 floats = 392 float4 per wave
#define WF4 (WFLOATS / 4)             // 392
#define BROWS (WROWS * 4)             // 128 rows per 256-thread block

__global__ __launch_bounds__(256, 6) void mdp_feat_sal_kernel(
    const float* __restrict__ x, const float* __restrict__ s,
    const float* __restrict__ fm, const int* __restrict__ sidx,
    float* __restrict__ out, int BC, int nb1, int N, int SHW, int qper)
{
    const int tid  = threadIdx.x;
    const int wid  = tid >> 6;        // wave in block (0..3)
    const int lane = tid & 63;

    if ((int)blockIdx.x < nb1) {
        __shared__ float xs[4 * WFLOATS];       // 25088 B, one slice per wave
        float* slice = &xs[wid * WFLOATS];

        // per-direction 1/count via ballot (SGPR-resident, per wave)
        float rc[8];
        #pragma unroll
        for (int p = 0; p < 8; ++p) {
            float v = (lane < KPIX) ? fm[p * KPIX + lane] : 0.f;
            unsigned long long bm = __ballot(v != 0.f);
            rc[p] = 1.0f / (float)__popcll(bm);
        }

        const int w0 = (blockIdx.x * 4 + wid) * WROWS;  // this wave's first row
        if (w0 >= BC) return;

        // ---- stage this wave's 32 rows (1568 floats), coalesced dwordx4 ----
        // base byte offset w0*196 = waveidx*6272, 6272 % 16 == 0 -> aligned
        const float4* xg = (const float4*)(x + (size_t)w0 * KPIX);
        float4* s4 = (float4*)slice;
        if (w0 + WROWS <= BC) {
            #pragma unroll
            for (int j = 0; j < 6; ++j) s4[j * 64 + lane] = xg[j * 64 + lane];
            if (lane < WF4 - 384) s4[384 + lane] = xg[384 + lane];  // last 8
        } else {
            const int nfl = (BC - w0) * KPIX;
            const float* xgs = x + (size_t)w0 * KPIX;
            for (int i = lane; i < nfl; i += 64) slice[i] = xgs[i];
        }
        // no barrier: same wave wrote and reads this slice; compiler emits
        // vmcnt/lgkmcnt ordering for the load->ds_write->ds_read chain.
        __builtin_amdgcn_s_waitcnt(0);   // drain vmcnt+lgkmcnt before reads

        // ---- compute: lane handles row w0+ (lane&31)? no: rows per lane ----
        // 32 rows, 64 lanes -> 2 lanes per row would waste; instead lanes 0..31
        // own rows, lanes 32..63 duplicate upper half? Simpler: each lane owns
        // row (lane % 32), lanes 32..63 handle nothing for compute but helped
        // stage. To keep all 64 busy: split the 8 directions: lane<32 does
        // p=0..3 for row lane, lane>=32 does p=4..7 for row lane-32.
        {
            const int rloc = lane & 31;
            const int r    = w0 + rloc;
            const int phalf = (lane >> 5) * 4;          // 0 or 4
            if (r < BC) {
                const float* row = &slice[rloc * KPIX]; // stride 49: conflict-free-ish
                float acc[4] = {0.f, 0.f, 0.f, 0.f};
                #pragma unroll
                for (int k = 0; k < KPIX; ++k) {
                    const float e = row[k];
                    #pragma unroll
                    for (int q = 0; q < 4; ++q)
                        acc[q] += e * fm[(phalf + q) * KPIX + k];  // uniform -> s_load
                }
                // lane<32 writes feat[r][0..3], lane>=32 writes feat[r][4..7]
                float4* o = (float4*)(out + (size_t)r * 8 + phalf);
                *o = make_float4(acc[0] * rc[phalf + 0], acc[1] * rc[phalf + 1],
                                 acc[2] * rc[phalf + 2], acc[3] * rc[phalf + 3]);
            }
        }
    } else {
        // ---- sal_feat path: qper blocks per batch row ----
        const int bq = blockIdx.x - nb1;
        const int b = bq / qper, q = bq % qper;
        const int tot = N * 8;
        const int chunk = tot / qper;
        const float* srow = s + (size_t)b * SHW;
        float* o2 = out + (size_t)BC * 8 + (size_t)b * tot + (size_t)q * chunk;
        for (int i = tid; i < chunk; i += 256) {
            const int e = q * chunk + i;
            o2[i] = srow[sidx[(e & 7) * N + (e >> 3)]];
        }
    }
}

extern "C" void kernel_launch(void* const* d_in, const int* in_sizes, int n_in,
                              void* d_out, int out_size, void* d_ws, size_t ws_size,
                              hipStream_t stream) {
    const float* x    = (const float*)d_in[0];
    const float* s    = (const float*)d_in[1];
    const float* fm   = (const float*)d_in[2];
    const int*   sidx = (const int*)d_in[3];
    float* out = (float*)d_out;

    const int SHW = 3136;                  // 56*56
    const int B   = in_sizes[1] / SHW;     // 256
    const int BC  = in_sizes[0] / KPIX;    // 524288
    const int N   = in_sizes[3] / 8;       // 406

    const int nb1  = (BC + BROWS - 1) / BROWS;          // 4096
    const int qper = ((N * 8) % 4 == 0) ? 4 : 1;        // 812-elem chunks
    const int grid = nb1 + B * qper;                    // 4096 + 1024

    mdp_feat_sal_kernel<<<grid, 256, 0, stream>>>(x, s, fm, sidx, out,
                                                  BC, nb1, N, SHW, qper);
}

// Round 9
// 166.359 us; speedup vs baseline: 1.1123x; 1.1123x over previous
//
#include <hip/hip_runtime.h>

//   x        : (B, C, 7, 7) fp32      -> in[0], B*C*49
//   s        : (B, 1, 56, 56) fp32    -> in[1], B*3136
//   feat_mask: (8, 7, 7) fp32         -> in[2], 392
//   sal_idx  : (8, N) int32           -> in[3], 8*N  (N = 406)
// out = [feat (B*C*8) | sal_feat (B*N*8)] fp32
//
// R9 = R8 with native ext_vector_type for the nontemporal builtins
// (HIP_vector_type<float,4> is a class -> rejected by the builtin).
// Theory: kernel shares HBM with harness poison fills (~1.3 TB/s leftover BW
// across R2-R7 regardless of structure/occupancy) -> minimize our HBM bytes;
// NT loads/stores keep our one-shot streams from evicting L3-warm x.

#define KPIX 49
#define TROWS 64
#define TFLOATS (TROWS * KPIX)   // 3136

typedef float vf4 __attribute__((ext_vector_type(4)));

__global__ __launch_bounds__(64, 3) void mdp_fused_kernel(
    const float* __restrict__ x, const float* __restrict__ s,
    const float* __restrict__ fm, const int* __restrict__ sidx,
    float* __restrict__ out, int BC, int nb1, int N, int SHW, int qper)
{
    const int lane = threadIdx.x;

    if ((int)blockIdx.x < nb1) {
        // ---- feat path: one wave, 64 rows ----
        __shared__ float xs[TFLOATS];
        const int r0 = blockIdx.x * TROWS;

        // per-direction 1/count via ballot (SGPR-resident)
        float rc[8];
        #pragma unroll
        for (int p = 0; p < 8; ++p) {
            float v = (lane < KPIX) ? fm[p * KPIX + lane] : 0.f;
            unsigned long long bm = __ballot(v != 0.f);
            rc[p] = 1.0f / (float)__popcll(bm);
        }

        // stage 64 rows (3136 floats) coalesced, non-temporal (read-once)
        const vf4* xg = (const vf4*)(x + (size_t)r0 * KPIX);  // 16B aligned
        vf4* xs4 = (vf4*)xs;
        if (r0 + TROWS <= BC) {
            #pragma unroll
            for (int j = 0; j < 12; ++j)
                xs4[j * 64 + lane] = __builtin_nontemporal_load(&xg[j * 64 + lane]);
            if (lane < 16)
                xs4[768 + lane] = __builtin_nontemporal_load(&xg[768 + lane]);
        } else {
            const int nfl = (BC - r0) * KPIX;
            const float* xgs = x + (size_t)r0 * KPIX;
            for (int i = lane; i < nfl; i += 64) xs[i] = xgs[i];
        }
        __syncthreads();   // single wave: just a waitcnt drain

        const int r = r0 + lane;
        if (r < BC) {
            float row[KPIX];   // stride-49 LDS reads: 2-way bank alias = free
            #pragma unroll
            for (int k = 0; k < KPIX; ++k) row[k] = xs[lane * KPIX + k];

            float sum[8];
            #pragma unroll
            for (int p = 0; p < 8; ++p) {
                float acc = 0.f;
                #pragma unroll
                for (int k = 0; k < KPIX; ++k)
                    acc += row[k] * fm[p * KPIX + k];   // uniform -> s_load/L1
                sum[p] = acc * rc[p];
            }
            vf4* o = (vf4*)(out + (size_t)r * 8);       // 32B aligned
            vf4 lo, hi;
            lo.x = sum[0]; lo.y = sum[1]; lo.z = sum[2]; lo.w = sum[3];
            hi.x = sum[4]; hi.y = sum[5]; hi.z = sum[6]; hi.w = sum[7];
            __builtin_nontemporal_store(lo, &o[0]);
            __builtin_nontemporal_store(hi, &o[1]);
        }
    } else {
        // ---- sal_feat path: qper blocks per batch row ----
        const int bq = blockIdx.x - nb1;
        const int b = bq / qper, q = bq % qper;
        const int tot = N * 8;
        const int chunk = tot / qper;
        const float* srow = s + (size_t)b * SHW;
        float* o2 = out + (size_t)BC * 8 + (size_t)b * tot + (size_t)q * chunk;
        for (int i = lane; i < chunk; i += 64) {
            const int e = q * chunk + i;
            const float v = srow[sidx[(e & 7) * N + (e >> 3)]];
            __builtin_nontemporal_store(v, &o2[i]);
        }
    }
}

extern "C" void kernel_launch(void* const* d_in, const int* in_sizes, int n_in,
                              void* d_out, int out_size, void* d_ws, size_t ws_size,
                              hipStream_t stream) {
    const float* x    = (const float*)d_in[0];
    const float* s    = (const float*)d_in[1];
    const float* fm   = (const float*)d_in[2];
    const int*   sidx = (const int*)d_in[3];
    float* out = (float*)d_out;

    const int SHW = 3136;                  // 56*56
    const int B   = in_sizes[1] / SHW;     // 256
    const int BC  = in_sizes[0] / KPIX;    // 524288
    const int N   = in_sizes[3] / 8;       // 406

    const int nb1  = (BC + TROWS - 1) / TROWS;          // 8192
    const int qper = ((N * 8) % 4 == 0) ? 4 : 1;        // 812-elem chunks
    const int grid = nb1 + B * qper;                    // 8192 + 1024

    mdp_fused_kernel<<<grid, 64, 0, stream>>>(x, s, fm, sidx, out,
                                              BC, nb1, N, SHW, qper);
}